// Round 8
// baseline (552.283 us; speedup 1.0000x reference)
//
#include <hip/hip_runtime.h>
#include <math.h>
#include <stdint.h>

// AxileAttention: out = softmax((X@Wq+bq)*(X@Wk+bk), -1) * (X@Wv+bv), per (b,c).
// B=8 C=64 H=256 W=256, fp32 in/out.
//
// Round 8: kill the 32x-redundant per-block W fp32->f16 conversion (75 us VALU
// + spill + latency inside the K-loop barriers in R7).
//  - Kernel A: one-shot convert of W into MFMA-fragment-ordered f16 planes in
//    d_ws: [c][kt][plane 0..4: qh,ql,kh,kl,vh][ntile 0..7][lane*16B]. 41.9 MB.
//  - Kernel B: R7 structure, W staged via async global_load_lds (dwordx4),
//    zero VALU; X still converted in-kernel (cheap). Two-phase K-loop caps
//    live acc at 128 regs. Falls back to R7 kernel if ws_size too small.

#define Bn 8
#define Cn 64
#define Hn 256
#define Wn 256

typedef _Float16 f16x8 __attribute__((ext_vector_type(8)));
typedef _Float16 f16x4 __attribute__((ext_vector_type(4)));
typedef float    f32x16 __attribute__((ext_vector_type(16)));

typedef __attribute__((address_space(1))) const uint32_t gl_u32;
typedef __attribute__((address_space(3))) uint32_t lds_u32;

#define MFMA(a, b, c) __builtin_amdgcn_mfma_f32_32x32x16_f16((a), (b), (c), 0, 0, 0)

// W' geometry (f16 units): plane = 4096, per-(c,kt) = 5*4096 = 20480
#define WP_PLANE 4096
#define WP_CKT   (5 * WP_PLANE)
#define WS_NEED  ((size_t)Cn * 16 * WP_CKT * sizeof(_Float16))   // 41,943,040 B

// LDS layout (37.5 KB):
//   A hi: [0,2048)       mtile*1024 + lane*16   (mtile 0..1)
//   A lo: [2048,4096)
//   B:    [4096,36864)   plane p*8192 + ntile*1024 + lane*16
//   smx:  [36864,38400)  part[64][4] @0, combmax[64] @1024, combsum[64] @1280
#define LDS_ALO 2048
#define LDS_B   4096
#define LDS_SM  36864

// ====================== Kernel A: W pre-conversion ======================
__global__ __launch_bounds__(256) void convert_w(
    const float* __restrict__ wq,
    const float* __restrict__ wk,
    const float* __restrict__ wv,
    _Float16* __restrict__ wc)
{
    const int gid   = blockIdx.x * 256 + threadIdx.x;   // 524288 total
    const int lane  = gid & 63;
    const int ntile = (gid >> 6) & 7;
    const int kt    = (gid >> 9) & 15;
    const int c     = gid >> 13;

    const int k0  = kt * 16 + (lane >> 5) * 8;
    const int col = ntile * 32 + (lane & 31);
    const size_t cb = (size_t)c * Wn * Wn;

    _Float16* dst = wc + ((size_t)c * 16 + kt) * WP_CKT;
    const int fo  = ntile * 512 + lane * 8;   // f16 offset inside a plane

    f16x8 qh, ql, kh, kl, vh;
#pragma unroll
    for (int e = 0; e < 8; ++e) {
        const size_t idx = cb + (size_t)(k0 + e) * Wn + col;
        const float q = wq[idx];
        const float k = wk[idx];
        const float v = wv[idx];
        _Float16 qhv = (_Float16)q;
        _Float16 khv = (_Float16)k;
        qh[e] = qhv; ql[e] = (_Float16)(q - (float)qhv);
        kh[e] = khv; kl[e] = (_Float16)(k - (float)khv);
        vh[e] = (_Float16)v;
    }
    *(f16x8*)(dst + 0 * WP_PLANE + fo) = qh;
    *(f16x8*)(dst + 1 * WP_PLANE + fo) = ql;
    *(f16x8*)(dst + 2 * WP_PLANE + fo) = kh;
    *(f16x8*)(dst + 3 * WP_PLANE + fo) = kl;
    *(f16x8*)(dst + 4 * WP_PLANE + fo) = vh;
}

// ====================== Kernel B: fused attention ======================
__global__ __launch_bounds__(256, 2) void axile_attn_mfma4(
    const float* __restrict__ x,
    const _Float16* __restrict__ wc,
    const float* __restrict__ bq,
    const float* __restrict__ bk,
    const float* __restrict__ bv,
    float* __restrict__ out)
{
    __shared__ __align__(16) char lds[38400];

    const int tid  = threadIdx.x;
    const int ncol = tid >> 6;     // wave id = column strip 0..3
    const int lane = tid & 63;
    const int h    = lane >> 5;
    const int l31  = lane & 31;

    const int blk = blockIdx.x;
    const int c   = blk & 63;      // XCD affinity per channel
    const int j   = blk >> 6;      // 0..31 = b*4 + ht
    const int b   = j >> 2;
    const int h0  = (j & 3) * 64;

    const float* xbase = x + ((size_t)(b * Cn + c) * Hn + h0) * Wn;
    const _Float16* wcc = wc + (size_t)c * 16 * WP_CKT;

    // X staging: thread = (row m = tid>>2, kq = tid&3) -> float4 of 4 k's.
    const int am    = tid >> 2;          // 0..63
    const int akq   = tid & 3;
    const int alc   = ((akq >> 1) << 5) | (am & 31);
    const int aboff = (akq & 1) * 8;
    const int amt   = am >> 5;

    f32x16 accq[2][2], acck[2][2];
#pragma unroll
    for (int mt = 0; mt < 2; ++mt)
#pragma unroll
        for (int nt = 0; nt < 2; ++nt)
#pragma unroll
            for (int r = 0; r < 16; ++r) {
                accq[mt][nt][r] = 0.f;
                acck[mt][nt][r] = 0.f;
            }

    // ================= phase 1: q,k =================
    for (int kt = 0; kt < 16; ++kt) {
        const int k0 = kt * 16;
        __syncthreads();
        // async-stage W' plane `ncol` (qh/ql/kh/kl), all 8 ntiles
        {
            const _Float16* srcp = wcc + (size_t)kt * WP_CKT + ncol * WP_PLANE + lane * 8;
            char* ldsp = lds + LDS_B + ncol * 8192;
#pragma unroll
            for (int nt8 = 0; nt8 < 8; ++nt8)
                __builtin_amdgcn_global_load_lds(
                    (gl_u32*)(srcp + nt8 * 512), (lds_u32*)(ldsp + nt8 * 1024), 16, 0, 0);
        }
        // stage X (hi+lo) with in-kernel split
        {
            const float4 xx = *(const float4*)(xbase + (size_t)am * Wn + k0 + akq * 4);
            f16x4 hi4, lo4;
            _Float16 t0 = (_Float16)xx.x; hi4[0] = t0; lo4[0] = (_Float16)(xx.x - (float)t0);
            _Float16 t1 = (_Float16)xx.y; hi4[1] = t1; lo4[1] = (_Float16)(xx.y - (float)t1);
            _Float16 t2 = (_Float16)xx.z; hi4[2] = t2; lo4[2] = (_Float16)(xx.z - (float)t2);
            _Float16 t3 = (_Float16)xx.w; hi4[3] = t3; lo4[3] = (_Float16)(xx.w - (float)t3);
            *(f16x4*)(lds + amt * 1024 + alc * 16 + aboff) = hi4;
            *(f16x4*)(lds + LDS_ALO + amt * 1024 + alc * 16 + aboff) = lo4;
        }
        __syncthreads();

        f16x8 ah[2], al[2];
#pragma unroll
        for (int mt = 0; mt < 2; ++mt) {
            ah[mt] = *(const f16x8*)(lds + mt * 1024 + lane * 16);
            al[mt] = *(const f16x8*)(lds + LDS_ALO + mt * 1024 + lane * 16);
        }
#pragma unroll
        for (int nt = 0; nt < 2; ++nt) {
            const int ntile = ncol * 2 + nt;
            const char* bb = lds + LDS_B + ntile * 1024 + lane * 16;
            f16x8 bqh = *(const f16x8*)(bb + 0 * 8192);
            f16x8 bql = *(const f16x8*)(bb + 1 * 8192);
            f16x8 bkh = *(const f16x8*)(bb + 2 * 8192);
            f16x8 bkl = *(const f16x8*)(bb + 3 * 8192);
#pragma unroll
            for (int mt = 0; mt < 2; ++mt) {
                accq[mt][nt] = MFMA(ah[mt], bqh, accq[mt][nt]);
                accq[mt][nt] = MFMA(al[mt], bqh, accq[mt][nt]);
                accq[mt][nt] = MFMA(ah[mt], bql, accq[mt][nt]);
                acck[mt][nt] = MFMA(ah[mt], bkh, acck[mt][nt]);
                acck[mt][nt] = MFMA(al[mt], bkh, acck[mt][nt]);
                acck[mt][nt] = MFMA(ah[mt], bkl, acck[mt][nt]);
            }
        }
    }

    float* part    = (float*)(lds + LDS_SM);          // [64][4]
    float* combmax = (float*)(lds + LDS_SM + 1024);   // [64]
    float* combsum = (float*)(lds + LDS_SM + 1280);   // [64]

    // ---- bias add; s = q*k into accq (acck dies here) ----
#pragma unroll
    for (int mt = 0; mt < 2; ++mt)
#pragma unroll
        for (int nt = 0; nt < 2; ++nt)
#pragma unroll
            for (int r = 0; r < 16; ++r) {
                const int rl = (r & 3) + 8 * (r >> 2) + 4 * h;
                const int hh = h0 + mt * 32 + rl;
                const int vv = ncol * 64 + nt * 32 + l31;
                const size_t bidx = ((size_t)c * Hn + hh) * Wn + vv;
                const float qv = accq[mt][nt][r] + bq[bidx];
                const float kv = acck[mt][nt][r] + bk[bidx];
                accq[mt][nt][r] = qv * kv;
            }

    // ---- row max ----
#pragma unroll
    for (int mt = 0; mt < 2; ++mt)
#pragma unroll
        for (int r = 0; r < 16; ++r) {
            float m2 = fmaxf(accq[mt][0][r], accq[mt][1][r]);
#pragma unroll
            for (int off = 16; off > 0; off >>= 1)
                m2 = fmaxf(m2, __shfl_xor(m2, off, 64));
            if ((lane & 15) == r && ((lane >> 4) & 1) == mt) {
                const int rl  = (r & 3) + 8 * (r >> 2) + 4 * h;
                part[(mt * 32 + rl) * 4 + ncol] = m2;
            }
        }
    __syncthreads();
    if (tid < 64)
        combmax[tid] = fmaxf(fmaxf(part[tid * 4 + 0], part[tid * 4 + 1]),
                             fmaxf(part[tid * 4 + 2], part[tid * 4 + 3]));
    __syncthreads();

    // ---- e = exp(s - mx) into accq; row sum ----
#pragma unroll
    for (int mt = 0; mt < 2; ++mt)
#pragma unroll
        for (int r = 0; r < 16; ++r) {
            const int rl  = (r & 3) + 8 * (r >> 2) + 4 * h;
            const int row = mt * 32 + rl;
            const float mx = combmax[row];
            const float e0 = __expf(accq[mt][0][r] - mx);
            const float e1 = __expf(accq[mt][1][r] - mx);
            accq[mt][0][r] = e0;
            accq[mt][1][r] = e1;
            float ps = e0 + e1;
#pragma unroll
            for (int off = 16; off > 0; off >>= 1)
                ps += __shfl_xor(ps, off, 64);
            if ((lane & 15) == r && ((lane >> 4) & 1) == mt)
                part[row * 4 + ncol] = ps;
        }
    __syncthreads();
    if (tid < 64)
        combsum[tid] = (part[tid * 4 + 0] + part[tid * 4 + 1]) +
                       (part[tid * 4 + 2] + part[tid * 4 + 3]);
    // (phase-2 first barrier covers combsum visibility)

    // ================= phase 2: v =================
    f32x16 accv[2][2];
#pragma unroll
    for (int mt = 0; mt < 2; ++mt)
#pragma unroll
        for (int nt = 0; nt < 2; ++nt)
#pragma unroll
            for (int r = 0; r < 16; ++r)
                accv[mt][nt][r] = 0.f;

    for (int kt = 0; kt < 16; ++kt) {
        const int k0 = kt * 16;
        __syncthreads();
        // async-stage W' plane 4 (vh): wave ncol takes ntiles 2*ncol, 2*ncol+1
        {
            const _Float16* srcp = wcc + (size_t)kt * WP_CKT + 4 * WP_PLANE + lane * 8;
#pragma unroll
            for (int i = 0; i < 2; ++i) {
                const int nt8 = ncol * 2 + i;
                __builtin_amdgcn_global_load_lds(
                    (gl_u32*)(srcp + nt8 * 512),
                    (lds_u32*)(lds + LDS_B + nt8 * 1024), 16, 0, 0);
            }
        }
        // stage X (hi only)
        {
            const float4 xx = *(const float4*)(xbase + (size_t)am * Wn + k0 + akq * 4);
            f16x4 hi4;
            hi4[0] = (_Float16)xx.x;
            hi4[1] = (_Float16)xx.y;
            hi4[2] = (_Float16)xx.z;
            hi4[3] = (_Float16)xx.w;
            *(f16x4*)(lds + amt * 1024 + alc * 16 + aboff) = hi4;
        }
        __syncthreads();

        f16x8 ah[2];
#pragma unroll
        for (int mt = 0; mt < 2; ++mt)
            ah[mt] = *(const f16x8*)(lds + mt * 1024 + lane * 16);
#pragma unroll
        for (int nt = 0; nt < 2; ++nt) {
            const int ntile = ncol * 2 + nt;
            f16x8 bvh = *(const f16x8*)(lds + LDS_B + ntile * 1024 + lane * 16);
#pragma unroll
            for (int mt = 0; mt < 2; ++mt)
                accv[mt][nt] = MFMA(ah[mt], bvh, accv[mt][nt]);
        }
    }

    // ---- out = e * (v + bv) / sum ----
    float* obase = out + ((size_t)(b * Cn + c) * Hn) * Wn;
#pragma unroll
    for (int mt = 0; mt < 2; ++mt)
#pragma unroll
        for (int r = 0; r < 16; ++r) {
            const int rl  = (r & 3) + 8 * (r >> 2) + 4 * h;
            const int row = mt * 32 + rl;
            const float inv = 1.0f / combsum[row];
            const int hh = h0 + row;
#pragma unroll
            for (int nt = 0; nt < 2; ++nt) {
                const int vv = ncol * 64 + nt * 32 + l31;
                const size_t bidx = ((size_t)c * Hn + hh) * Wn + vv;
                const float vx = accv[mt][nt][r] + bv[bidx];
                obase[(size_t)hh * Wn + vv] = accq[mt][nt][r] * vx * inv;
            }
        }
}

// ====================== Fallback (R7, proven) ======================
__global__ __launch_bounds__(256, 2) void axile_attn_mfma3(
    const float* __restrict__ x,
    const float* __restrict__ wq,
    const float* __restrict__ wk,
    const float* __restrict__ wv,
    const float* __restrict__ bq,
    const float* __restrict__ bk,
    const float* __restrict__ bv,
    float* __restrict__ out)
{
    __shared__ __align__(16) char lds[38400];
    const int tid  = threadIdx.x;
    const int ncol = tid >> 6;
    const int lane = tid & 63;
    const int h    = lane >> 5;
    const int l31  = lane & 31;
    const int blk = blockIdx.x;
    const int c   = blk & 63;
    const int j   = blk >> 6;
    const int b   = j >> 2;
    const int h0  = (j & 3) * 64;
    const float* xbase = x + ((size_t)(b * Cn + c) * Hn + h0) * Wn;
    const float* w_q = wq + (size_t)c * Wn * Wn;
    const float* w_k = wk + (size_t)c * Wn * Wn;
    const float* w_v = wv + (size_t)c * Wn * Wn;
    const int n    = tid;
    const int ntW  = n >> 5;
    const int nl   = n & 31;
    const int am    = tid >> 2;
    const int akq   = tid & 3;
    const int amt   = am >> 5;
    const int alc   = ((akq >> 1) << 5) | (am & 31);
    const int aboff = (akq & 1) * 8;
    f32x16 accq[2][2], acck[2][2];
#pragma unroll
    for (int mt = 0; mt < 2; ++mt)
#pragma unroll
        for (int nt = 0; nt < 2; ++nt)
#pragma unroll
            for (int r = 0; r < 16; ++r) { accq[mt][nt][r] = 0.f; acck[mt][nt][r] = 0.f; }
    for (int kt = 0; kt < 16; ++kt) {
        const int k0 = kt * 16;
        __syncthreads();
#pragma unroll
        for (int mat = 0; mat < 2; ++mat) {
            const float* Wp = mat ? w_k : w_q;
            float w16[16];
#pragma unroll
            for (int r = 0; r < 16; ++r) w16[r] = Wp[(size_t)(k0 + r) * Wn + n];
            char* dplane = lds + LDS_B + (mat * 2) * 8192 + ntW * 1024;
#pragma unroll
            for (int h2 = 0; h2 < 2; ++h2) {
                f16x8 hi8, lo8;
#pragma unroll
                for (int e = 0; e < 8; ++e) {
                    const float wv_ = w16[h2 * 8 + e];
                    _Float16 hv = (_Float16)wv_;
                    hi8[e] = hv; lo8[e] = (_Float16)(wv_ - (float)hv);
                }
                const int fo = ((h2 << 5) | nl) * 16;
                *(f16x8*)(dplane + fo) = hi8;
                *(f16x8*)(dplane + 8192 + fo) = lo8;
            }
        }
        {
            const float4 xx = *(const float4*)(xbase + (size_t)am * Wn + k0 + akq * 4);
            f16x4 hi4, lo4;
            _Float16 t0 = (_Float16)xx.x; hi4[0] = t0; lo4[0] = (_Float16)(xx.x - (float)t0);
            _Float16 t1 = (_Float16)xx.y; hi4[1] = t1; lo4[1] = (_Float16)(xx.y - (float)t1);
            _Float16 t2 = (_Float16)xx.z; hi4[2] = t2; lo4[2] = (_Float16)(xx.z - (float)t2);
            _Float16 t3 = (_Float16)xx.w; hi4[3] = t3; lo4[3] = (_Float16)(xx.w - (float)t3);
            *(f16x4*)(lds + amt * 1024 + alc * 16 + aboff) = hi4;
            *(f16x4*)(lds + LDS_ALO + amt * 1024 + alc * 16 + aboff) = lo4;
        }
        __syncthreads();
        f16x8 ah[2], al[2];
#pragma unroll
        for (int mt = 0; mt < 2; ++mt) {
            ah[mt] = *(const f16x8*)(lds + mt * 1024 + lane * 16);
            al[mt] = *(const f16x8*)(lds + LDS_ALO + mt * 1024 + lane * 16);
        }
#pragma unroll
        for (int nt = 0; nt < 2; ++nt) {
            const int ntile = ncol * 2 + nt;
            const char* bb = lds + LDS_B + ntile * 1024 + lane * 16;
            f16x8 bqh = *(const f16x8*)(bb + 0 * 8192);
            f16x8 bql = *(const f16x8*)(bb + 1 * 8192);
            f16x8 bkh = *(const f16x8*)(bb + 2 * 8192);
            f16x8 bkl = *(const f16x8*)(bb + 3 * 8192);
#pragma unroll
            for (int mt = 0; mt < 2; ++mt) {
                accq[mt][nt] = MFMA(ah[mt], bqh, accq[mt][nt]);
                accq[mt][nt] = MFMA(al[mt], bqh, accq[mt][nt]);
                accq[mt][nt] = MFMA(ah[mt], bql, accq[mt][nt]);
                acck[mt][nt] = MFMA(ah[mt], bkh, acck[mt][nt]);
                acck[mt][nt] = MFMA(al[mt], bkh, acck[mt][nt]);
                acck[mt][nt] = MFMA(ah[mt], bkl, acck[mt][nt]);
            }
        }
    }
    float* part    = (float*)(lds + LDS_SM);
    float* combmax = (float*)(lds + LDS_SM + 1024);
    float* combsum = (float*)(lds + LDS_SM + 1280);
#pragma unroll
    for (int mt = 0; mt < 2; ++mt)
#pragma unroll
        for (int nt = 0; nt < 2; ++nt)
#pragma unroll
            for (int r = 0; r < 16; ++r) {
                const int rl = (r & 3) + 8 * (r >> 2) + 4 * h;
                const int hh = h0 + mt * 32 + rl;
                const int vv = ncol * 64 + nt * 32 + l31;
                const size_t bidx = ((size_t)c * Hn + hh) * Wn + vv;
                accq[mt][nt][r] = (accq[mt][nt][r] + bq[bidx]) * (acck[mt][nt][r] + bk[bidx]);
            }
#pragma unroll
    for (int mt = 0; mt < 2; ++mt)
#pragma unroll
        for (int r = 0; r < 16; ++r) {
            float m2 = fmaxf(accq[mt][0][r], accq[mt][1][r]);
#pragma unroll
            for (int off = 16; off > 0; off >>= 1) m2 = fmaxf(m2, __shfl_xor(m2, off, 64));
            if ((lane & 15) == r && ((lane >> 4) & 1) == mt) {
                const int rl  = (r & 3) + 8 * (r >> 2) + 4 * h;
                part[(mt * 32 + rl) * 4 + ncol] = m2;
            }
        }
    __syncthreads();
    if (tid < 64)
        combmax[tid] = fmaxf(fmaxf(part[tid * 4 + 0], part[tid * 4 + 1]),
                             fmaxf(part[tid * 4 + 2], part[tid * 4 + 3]));
    __syncthreads();
#pragma unroll
    for (int mt = 0; mt < 2; ++mt)
#pragma unroll
        for (int r = 0; r < 16; ++r) {
            const int rl  = (r & 3) + 8 * (r >> 2) + 4 * h;
            const int row = mt * 32 + rl;
            const float mx = combmax[row];
            const float e0 = __expf(accq[mt][0][r] - mx);
            const float e1 = __expf(accq[mt][1][r] - mx);
            accq[mt][0][r] = e0; accq[mt][1][r] = e1;
            float ps = e0 + e1;
#pragma unroll
            for (int off = 16; off > 0; off >>= 1) ps += __shfl_xor(ps, off, 64);
            if ((lane & 15) == r && ((lane >> 4) & 1) == mt) part[row * 4 + ncol] = ps;
        }
    __syncthreads();
    if (tid < 64)
        combsum[tid] = (part[tid * 4 + 0] + part[tid * 4 + 1]) +
                       (part[tid * 4 + 2] + part[tid * 4 + 3]);
    f32x16 accv[2][2];
#pragma unroll
    for (int mt = 0; mt < 2; ++mt)
#pragma unroll
        for (int nt = 0; nt < 2; ++nt)
#pragma unroll
            for (int r = 0; r < 16; ++r) accv[mt][nt][r] = 0.f;
    for (int kt = 0; kt < 16; ++kt) {
        const int k0 = kt * 16;
        __syncthreads();
        {
            float w16[16];
#pragma unroll
            for (int r = 0; r < 16; ++r) w16[r] = w_v[(size_t)(k0 + r) * Wn + n];
            char* dplane = lds + LDS_B + ntW * 1024;
#pragma unroll
            for (int h2 = 0; h2 < 2; ++h2) {
                f16x8 hi8;
#pragma unroll
                for (int e = 0; e < 8; ++e) hi8[e] = (_Float16)w16[h2 * 8 + e];
                *(f16x8*)(dplane + ((h2 << 5) | nl) * 16) = hi8;
            }
        }
        {
            const float4 xx = *(const float4*)(xbase + (size_t)am * Wn + k0 + akq * 4);
            f16x4 hi4;
            hi4[0] = (_Float16)xx.x; hi4[1] = (_Float16)xx.y;
            hi4[2] = (_Float16)xx.z; hi4[3] = (_Float16)xx.w;
            *(f16x4*)(lds + amt * 1024 + alc * 16 + aboff) = hi4;
        }
        __syncthreads();
        f16x8 ah[2];
#pragma unroll
        for (int mt = 0; mt < 2; ++mt)
            ah[mt] = *(const f16x8*)(lds + mt * 1024 + lane * 16);
#pragma unroll
        for (int nt = 0; nt < 2; ++nt) {
            f16x8 bvh = *(const f16x8*)(lds + LDS_B + (ncol * 2 + nt) * 1024 + lane * 16);
#pragma unroll
            for (int mt = 0; mt < 2; ++mt)
                accv[mt][nt] = MFMA(ah[mt], bvh, accv[mt][nt]);
        }
    }
    float* obase = out + ((size_t)(b * Cn + c) * Hn) * Wn;
#pragma unroll
    for (int mt = 0; mt < 2; ++mt)
#pragma unroll
        for (int r = 0; r < 16; ++r) {
            const int rl  = (r & 3) + 8 * (r >> 2) + 4 * h;
            const int row = mt * 32 + rl;
            const float inv = 1.0f / combsum[row];
            const int hh = h0 + row;
#pragma unroll
            for (int nt = 0; nt < 2; ++nt) {
                const int vv = ncol * 64 + nt * 32 + l31;
                const size_t bidx = ((size_t)c * Hn + hh) * Wn + vv;
                obase[(size_t)hh * Wn + vv] = accq[mt][nt][r] * (accv[mt][nt][r] + bv[bidx]) * inv;
            }
        }
}

extern "C" void kernel_launch(void* const* d_in, const int* in_sizes, int n_in,
                              void* d_out, int out_size, void* d_ws, size_t ws_size,
                              hipStream_t stream) {
    (void)in_sizes; (void)n_in; (void)out_size;
    const float* x  = (const float*)d_in[0];
    const float* wq = (const float*)d_in[1];
    const float* wk = (const float*)d_in[2];
    const float* wv = (const float*)d_in[3];
    const float* bq = (const float*)d_in[4];
    const float* bk = (const float*)d_in[5];
    const float* bv = (const float*)d_in[6];
    float* out = (float*)d_out;

    if (ws_size >= WS_NEED) {
        _Float16* wc = (_Float16*)d_ws;
        hipLaunchKernelGGL(convert_w, dim3(2048), dim3(256), 0, stream, wq, wk, wv, wc);
        hipLaunchKernelGGL(axile_attn_mfma4, dim3(Bn * 4 * Cn), dim3(256), 0, stream,
                           x, wc, bq, bk, bv, out);
    } else {
        hipLaunchKernelGGL(axile_attn_mfma3, dim3(Bn * 4 * Cn), dim3(256), 0, stream,
                           x, wq, wk, wv, bq, bk, bv, out);
    }
}